// Round 1
// baseline (355.691 us; speedup 1.0000x reference)
//
#include <hip/hip_runtime.h>
#include <hip/hip_fp16.h>

#define S_TOK 8192
#define DDIM  1024
#define HDIM  4096
#define NEXP  8
#define CAP   1024

typedef __attribute__((ext_vector_type(8))) _Float16 half8;
typedef __attribute__((ext_vector_type(2))) _Float16 half2v;
typedef __attribute__((ext_vector_type(4))) float f32x4;

__device__ __forceinline__ void load_lds16(const _Float16* g, _Float16* l) {
  __builtin_amdgcn_global_load_lds(
      (const __attribute__((address_space(1))) unsigned int*)g,
      (__attribute__((address_space(3))) unsigned int*)l, 16, 0, 0);
}

// ---------------- gating: logits = x @ wg, softmax, top-1 ----------------
__global__ __launch_bounds__(64) void moe_gating(const float* __restrict__ x,
                                                 const float* __restrict__ wg,
                                                 int* __restrict__ eidx,
                                                 float* __restrict__ gtok) {
  const int s = blockIdx.x;
  const int lane = threadIdx.x;
  const float* xr = x + (size_t)s * DDIM;
  float acc[NEXP];
#pragma unroll
  for (int e = 0; e < NEXP; ++e) acc[e] = 0.f;
  for (int d = lane; d < DDIM; d += 64) {
    float xv = xr[d];
    const float4* wrow = (const float4*)(wg + (size_t)d * NEXP);
    float4 w0 = wrow[0], w1v = wrow[1];
    acc[0] += xv * w0.x;  acc[1] += xv * w0.y;
    acc[2] += xv * w0.z;  acc[3] += xv * w0.w;
    acc[4] += xv * w1v.x; acc[5] += xv * w1v.y;
    acc[6] += xv * w1v.z; acc[7] += xv * w1v.w;
  }
#pragma unroll
  for (int off = 32; off > 0; off >>= 1) {
#pragma unroll
    for (int e = 0; e < NEXP; ++e) acc[e] += __shfl_down(acc[e], off);
  }
  if (lane == 0) {
    int best = 0; float bv = acc[0];
#pragma unroll
    for (int e = 1; e < NEXP; ++e) if (acc[e] > bv) { bv = acc[e]; best = e; }
    float sum = 0.f;
#pragma unroll
    for (int e = 0; e < NEXP; ++e) sum += expf(acc[e] - bv);
    eidx[s] = best;
    gtok[s] = 1.f / sum;   // exp(best - max) == 1
  }
}

// ---------------- ordered slot assignment (cumsum semantics) ----------------
__global__ __launch_bounds__(512) void moe_scan(const int* __restrict__ eidx,
                                                const float* __restrict__ gtok,
                                                int* __restrict__ s2t,
                                                float* __restrict__ rgate) {
  const int tid = threadIdx.x;
  for (int i = tid; i < NEXP * CAP; i += 512) { s2t[i] = -1; rgate[i] = 0.f; }
  __syncthreads();
  const int w = tid >> 6, lane = tid & 63;
  const unsigned long long below = (1ull << lane) - 1ull;
  int count = 0;
  int e_next = eidx[lane];
  float g_next = gtok[lane];
  for (int base = 0; base < S_TOK; base += 64) {
    int e = e_next; float g = g_next;
    if (base + 64 < S_TOK) { e_next = eidx[base + 64 + lane]; g_next = gtok[base + 64 + lane]; }
    unsigned long long mask = __ballot(e == w);
    if (e == w) {
      int slot = count + __popcll(mask & below);
      if (slot < CAP) { s2t[w * CAP + slot] = base + lane; rgate[w * CAP + slot] = g; }
    }
    count += __popcll(mask);
  }
}

// ---------------- dispatch: gather kept tokens, fp32 -> fp16 ----------------
__global__ __launch_bounds__(128) void moe_dispatch(const float* __restrict__ x,
                                                    const int* __restrict__ s2t,
                                                    _Float16* __restrict__ disp) {
  const int row = blockIdx.x;
  const int t = threadIdx.x;
  const int token = s2t[row];
  half8 v;
  if (token >= 0) {
    const float4* xr = (const float4*)(x + (size_t)token * DDIM);
    float4 a = xr[2 * t], b = xr[2 * t + 1];
    v[0] = (_Float16)a.x; v[1] = (_Float16)a.y; v[2] = (_Float16)a.z; v[3] = (_Float16)a.w;
    v[4] = (_Float16)b.x; v[5] = (_Float16)b.y; v[6] = (_Float16)b.z; v[7] = (_Float16)b.w;
  } else {
#pragma unroll
    for (int i = 0; i < 8; ++i) v[i] = (_Float16)0.f;
  }
  *(half8*)(disp + (size_t)row * DDIM + t * 8) = v;
}

// ---------------- transpose + fp32->fp16 convert: in[R][Cc] -> out[Cc][R] ----------------
__global__ __launch_bounds__(256) void transpose_cvt(const float* __restrict__ in,
                                                     _Float16* __restrict__ out,
                                                     int R, int Cc) {
  __shared__ float tile[64][65];
  const size_t mat = (size_t)R * Cc;
  const float* ip = in + (size_t)blockIdx.z * mat;
  _Float16* op = out + (size_t)blockIdx.z * mat;
  const int r0 = blockIdx.y * 64, c0 = blockIdx.x * 64;
  const int tx = threadIdx.x & 63, ty = threadIdx.x >> 6;
#pragma unroll
  for (int i = 0; i < 16; ++i) {
    int rl = ty * 16 + i;
    tile[rl][tx] = ip[(size_t)(r0 + rl) * Cc + c0 + tx];
  }
  __syncthreads();
  const int tx2 = threadIdx.x & 31, ty2 = threadIdx.x >> 5;
#pragma unroll
  for (int i = 0; i < 8; ++i) {
    int cl = ty2 * 8 + i;
    int rl = tx2 * 2;
    half2v v;
    v[0] = (_Float16)tile[rl][cl];
    v[1] = (_Float16)tile[rl + 1][cl];
    *(half2v*)(op + (size_t)(c0 + cl) * R + r0 + rl) = v;
  }
}

// ---------------- grouped GEMM: out = A[z] @ B[z]^T (B stored [N][K]) ----------------
// FIRST: out = relu -> fp16 Hout.  !FIRST: scatter fp32 to Y via slot2token * gate.
template <int KDIM, int NDIM, bool FIRST>
__global__ __launch_bounds__(256) void ffn_gemm(const _Float16* __restrict__ A_set,
                                                const _Float16* __restrict__ B_set,
                                                _Float16* __restrict__ Hout,
                                                float* __restrict__ Y,
                                                const int* __restrict__ s2t,
                                                const float* __restrict__ rgate,
                                                int e_base) {
  __shared__ _Float16 As[128 * 32];
  __shared__ _Float16 Bs[128 * 32];
  const int z = blockIdx.z;
  const int m0 = blockIdx.y * 128;
  const int n0 = blockIdx.x * 128;
  const int tid = threadIdx.x;
  const int lane = tid & 63;
  const int wr = tid >> 7;          // wave row (0..1)
  const int wc = (tid >> 6) & 1;    // wave col (0..1)

  const _Float16* Ae = A_set + (size_t)z * 1024 * KDIM;
  const _Float16* Be = B_set + (size_t)z * (size_t)NDIM * KDIM;

  const int row_a = tid >> 2;       // staging row 0..63 (second issue adds 64)
  const int kp = (tid & 3) * 8;     // k sub-offset (8 halfs = 16B)

  f32x4 acc[4][4];
#pragma unroll
  for (int m = 0; m < 4; ++m)
#pragma unroll
    for (int n = 0; n < 4; ++n) acc[m][n] = {0.f, 0.f, 0.f, 0.f};

  for (int k0 = 0; k0 < KDIM; k0 += 32) {
    __syncthreads();
    load_lds16(Ae + (size_t)(m0 + row_a) * KDIM + k0 + kp, As + tid * 8);
    load_lds16(Ae + (size_t)(m0 + 64 + row_a) * KDIM + k0 + kp, As + 2048 + tid * 8);
    load_lds16(Be + (size_t)(n0 + row_a) * KDIM + k0 + kp, Bs + tid * 8);
    load_lds16(Be + (size_t)(n0 + 64 + row_a) * KDIM + k0 + kp, Bs + 2048 + tid * 8);
    __syncthreads();
    half8 af[4], bf[4];
#pragma unroll
    for (int m = 0; m < 4; ++m)
      af[m] = *(const half8*)(As + (wr * 64 + m * 16 + (lane & 15)) * 32 + (lane >> 4) * 8);
#pragma unroll
    for (int n = 0; n < 4; ++n)
      bf[n] = *(const half8*)(Bs + (wc * 64 + n * 16 + (lane & 15)) * 32 + (lane >> 4) * 8);
#pragma unroll
    for (int m = 0; m < 4; ++m)
#pragma unroll
      for (int n = 0; n < 4; ++n)
        acc[m][n] = __builtin_amdgcn_mfma_f32_16x16x32_f16(af[m], bf[n], acc[m][n], 0, 0, 0);
  }

  const int rbase = wr * 64 + (lane >> 4) * 4;   // + m*16 + j
  const int cbase = n0 + wc * 64 + (lane & 15);  // + n*16
  if (FIRST) {
#pragma unroll
    for (int m = 0; m < 4; ++m) {
      int row = m0 + rbase + m * 16;
#pragma unroll
      for (int n = 0; n < 4; ++n) {
        int col = cbase + n * 16;
#pragma unroll
        for (int j = 0; j < 4; ++j) {
          float v = fmaxf(acc[m][n][j], 0.f);
          Hout[((size_t)z * 1024 + row + j) * NDIM + col] = (_Float16)v;
        }
      }
    }
  } else {
#pragma unroll
    for (int m = 0; m < 4; ++m) {
      int srow = (e_base + z) * CAP + m0 + rbase + m * 16;
#pragma unroll
      for (int j = 0; j < 4; ++j) {
        int token = s2t[srow + j];
        if (token < 0) continue;
        float g = rgate[srow + j];
#pragma unroll
        for (int n = 0; n < 4; ++n) {
          int col = cbase + n * 16;
          Y[(size_t)token * DDIM + col] = acc[m][n][j] * g;
        }
      }
    }
  }
}

extern "C" void kernel_launch(void* const* d_in, const int* in_sizes, int n_in,
                              void* d_out, int out_size, void* d_ws, size_t ws_size,
                              hipStream_t stream) {
  const float* x  = (const float*)d_in[0];
  const float* wg = (const float*)d_in[1];
  const float* w1 = (const float*)d_in[2];
  const float* w2 = (const float*)d_in[3];
  float* y = (float*)d_out;

  char* ws = (char*)d_ws;
  int*   eidx  = (int*)(ws);
  float* gtok  = (float*)(ws + 32768);
  int*   s2t   = (int*)(ws + 65536);
  float* rgate = (float*)(ws + 98304);
  _Float16* disp = (_Float16*)(ws + 131072);
  char* big = ws + 131072 + (size_t)NEXP * CAP * DDIM * 2;  // after disp (16 MB)

  moe_gating<<<S_TOK, 64, 0, stream>>>(x, wg, eidx, gtok);
  moe_scan<<<1, 512, 0, stream>>>(eidx, gtok, s2t, rgate);
  moe_dispatch<<<NEXP * CAP, 128, 0, stream>>>(x, s2t, disp);
  (void)hipMemsetAsync(d_out, 0, (size_t)out_size * sizeof(float), stream);

  const size_t PLAN_A = 131072ull + 16777216ull + 67108864ull + 67108864ull;
  if (ws_size >= PLAN_A) {
    _Float16* hbuf = (_Float16*)big;                  // [E][C][H] fp16, 67 MB
    _Float16* wt   = (_Float16*)(big + 67108864);     // shared w1t then w2t, 67 MB
    transpose_cvt<<<dim3(HDIM / 64, DDIM / 64, NEXP), 256, 0, stream>>>(w1, wt, DDIM, HDIM);
    ffn_gemm<DDIM, HDIM, true><<<dim3(HDIM / 128, CAP / 128, NEXP), 256, 0, stream>>>(
        disp, wt, hbuf, nullptr, nullptr, nullptr, 0);
    transpose_cvt<<<dim3(DDIM / 64, HDIM / 64, NEXP), 256, 0, stream>>>(w2, wt, HDIM, DDIM);
    ffn_gemm<HDIM, DDIM, false><<<dim3(DDIM / 128, CAP / 128, NEXP), 256, 0, stream>>>(
        hbuf, wt, nullptr, y, s2t, rgate, 0);
  } else {
    // small-workspace fallback: per-expert loop, ~34 MB
    _Float16* h_e = (_Float16*)big;                   // [C][H] fp16, 8.4 MB
    _Float16* wt  = (_Float16*)(big + 8388608);       // 8.4 MB
    for (int e = 0; e < NEXP; ++e) {
      transpose_cvt<<<dim3(HDIM / 64, DDIM / 64, 1), 256, 0, stream>>>(
          w1 + (size_t)e * DDIM * HDIM, wt, DDIM, HDIM);
      ffn_gemm<DDIM, HDIM, true><<<dim3(HDIM / 128, CAP / 128, 1), 256, 0, stream>>>(
          disp + (size_t)e * CAP * DDIM, wt, h_e, nullptr, nullptr, nullptr, e);
      transpose_cvt<<<dim3(DDIM / 64, HDIM / 64, 1), 256, 0, stream>>>(
          w2 + (size_t)e * HDIM * DDIM, wt, HDIM, DDIM);
      ffn_gemm<HDIM, DDIM, false><<<dim3(DDIM / 128, CAP / 128, 1), 256, 0, stream>>>(
          h_e, wt, nullptr, y, s2t, rgate, e);
    }
  }
}